// Round 2
// baseline (441.747 us; speedup 1.0000x reference)
//
#include <hip/hip_runtime.h>
#include <math.h>

namespace {
constexpr int B_   = 8;
constexpr int DIM_ = 2048;
constexpr int H_   = 16;
constexpr int QLR_ = 1536;
constexpr int KVLR_= 512;
constexpr int DN_  = 128;
constexpr int DR_  = 64;
constexpr int DV_  = 128;
constexpr int TPRE_= 8191;
constexpr int CE_  = 576;    // KVLR + DR
constexpr int NCH_ = 64;     // chunks over T=8192
constexpr int CT_  = 128;    // t per chunk
constexpr float EPS_ = 1e-6f;
constexpr float SCALE_ = 0.07216878364870322f; // (DN+DR)^-0.5

// workspace layout (float offsets)
constexpr size_t WS_QLAT  = 0;
constexpr size_t WS_KVPE  = WS_QLAT  + (size_t)B_*QLR_;
constexpr size_t WS_KVNEW = WS_KVPE  + (size_t)B_*CE_;
constexpr size_t WS_PENEW = WS_KVNEW + (size_t)B_*KVLR_;
constexpr size_t WS_QRS   = WS_PENEW + (size_t)B_*DR_;
constexpr size_t WS_QNOPE = WS_QRS   + (size_t)B_;
constexpr size_t WS_QT    = WS_QNOPE + (size_t)B_*H_*DN_;   // [b][576][16]
constexpr size_t WS_MLOC  = WS_QT    + (size_t)B_*CE_*H_;
constexpr size_t WS_LLOC  = WS_MLOC  + (size_t)B_*H_*NCH_;
constexpr size_t WS_OUT2  = WS_LLOC  + (size_t)B_*H_*NCH_;
constexpr size_t WS_OPART = WS_OUT2  + (size_t)B_*DIM_;     // [b][h][chunk][512]
} // namespace

// ---------------- K1: q_latent = x@wq_a^T + b ; kvpe = x@wkv_a^T + b ----------------
// 1 row per wave, x read directly from global (L2-hot, 64KB), no LDS.
__global__ __launch_bounds__(512) void mla_k1(const float* __restrict__ x,
                                              const float* __restrict__ wqa,
                                              const float* __restrict__ bqa,
                                              const float* __restrict__ wkva,
                                              const float* __restrict__ bkva,
                                              float* __restrict__ ws) {
  const int w = threadIdx.x >> 6, l = threadIdx.x & 63;
  const int r = blockIdx.x * 8 + w;  // 0..2111
  const float* W; const float* bias; float* out; int rr; int ostride;
  if (r < QLR_) { W = wqa;  bias = bqa;  out = ws + WS_QLAT; rr = r;        ostride = QLR_; }
  else          { W = wkva; bias = bkva; out = ws + WS_KVPE; rr = r - QLR_; ostride = CE_;  }
  float acc[B_];
#pragma unroll
  for (int b = 0; b < B_; ++b) acc[b] = 0.f;
  const float4* wp = (const float4*)(W + (size_t)rr * DIM_);
  const float4* x4 = (const float4*)x;
#pragma unroll
  for (int j = 0; j < DIM_ / 256; ++j) { // 8
    const int c4 = l + 64 * j;
    const float4 wv = wp[c4];
#pragma unroll
    for (int b = 0; b < B_; ++b) {
      const float4 xv = x4[b * (DIM_ / 4) + c4];
      acc[b] = fmaf(wv.x, xv.x, fmaf(wv.y, xv.y, fmaf(wv.z, xv.z, fmaf(wv.w, xv.w, acc[b]))));
    }
  }
#pragma unroll
  for (int b = 0; b < B_; ++b)
#pragma unroll
    for (int s = 32; s; s >>= 1) acc[b] += __shfl_xor(acc[b], s);
  if (l == 0) {
    const float b0 = bias[rr];
#pragma unroll
    for (int b = 0; b < B_; ++b) out[b * ostride + rr] = acc[b] + b0;
  }
}

// ---------------- K2: kv rms-norm + k_pe rope + q rms scales ----------------
__global__ __launch_bounds__(256) void mla_k2(const float* __restrict__ kvnw,
                                              const float* __restrict__ fcos,
                                              const float* __restrict__ fsin,
                                              float* __restrict__ ws) {
  const int tid = threadIdx.x;
  const int b = tid >> 5, i = tid & 31;
  const float* kvpe = ws + WS_KVPE + b * CE_;
  float ss = 0.f;
#pragma unroll
  for (int j = 0; j < KVLR_ / 32; ++j) { const float v = kvpe[i + 32 * j]; ss = fmaf(v, v, ss); }
#pragma unroll
  for (int s = 16; s; s >>= 1) ss += __shfl_xor(ss, s, 32);
  const float scale = 1.0f / sqrtf(ss / (float)KVLR_ + EPS_);
  float* kvn = ws + WS_KVNEW + b * KVLR_;
#pragma unroll
  for (int j = 0; j < KVLR_ / 32; ++j) {
    const int c = i + 32 * j;
    kvn[c] = kvpe[c] * kvnw[c] * scale;
  }
  { // rope new k_pe (32 pairs per batch)
    const float xr = kvpe[KVLR_ + 2 * i], xi = kvpe[KVLR_ + 2 * i + 1];
    const float c = fcos[i], s = fsin[i];
    float* pen = ws + WS_PENEW + b * DR_;
    pen[2 * i]     = xr * c - xi * s;
    pen[2 * i + 1] = xr * s + xi * c;
  }
  { // q latent rms scale per batch
    const float* p = ws + WS_QLAT + b * QLR_;
    float sq = 0.f;
#pragma unroll
    for (int j = 0; j < QLR_ / 32; ++j) { const float v = p[i + 32 * j]; sq = fmaf(v, v, sq); }
#pragma unroll
    for (int s = 16; s; s >>= 1) sq += __shfl_xor(sq, s, 32);
    if (i == 0) ws[WS_QRS + b] = 1.0f / sqrtf(sq / (float)QLR_ + EPS_);
  }
}

// ---------------- K3: q = rms(q_lat)*g @ wq_b^T + b ; split nope / rope(pe) ----------------
// norm folded into dot: acc_b = sum_c (w*g)[c]*qlat[b][c], scaled by qrs[b] at the end.
__global__ __launch_bounds__(256) void mla_k3(const float* __restrict__ qnw,
                                              const float* __restrict__ wqb,
                                              const float* __restrict__ bqb,
                                              const float* __restrict__ fcos,
                                              const float* __restrict__ fsin,
                                              float* __restrict__ ws) {
  const int w = threadIdx.x >> 6, l = threadIdx.x & 63;
  const int r0 = blockIdx.x * 8 + w * 2;  // 0..3070
  float acc0[B_], acc1[B_];
#pragma unroll
  for (int b = 0; b < B_; ++b) { acc0[b] = 0.f; acc1[b] = 0.f; }
  const float4* w0p = (const float4*)(wqb + (size_t)r0 * QLR_);
  const float4* w1p = (const float4*)(wqb + (size_t)(r0 + 1) * QLR_);
  const float4* g4  = (const float4*)qnw;
  const float4* x4  = (const float4*)(ws + WS_QLAT);
#pragma unroll
  for (int j = 0; j < QLR_ / 256; ++j) { // 6
    const int c4 = l + 64 * j;
    const float4 wv0 = w0p[c4];
    const float4 wv1 = w1p[c4];
    const float4 gv  = g4[c4];
    float4 wg0, wg1;
    wg0.x = wv0.x * gv.x; wg0.y = wv0.y * gv.y; wg0.z = wv0.z * gv.z; wg0.w = wv0.w * gv.w;
    wg1.x = wv1.x * gv.x; wg1.y = wv1.y * gv.y; wg1.z = wv1.z * gv.z; wg1.w = wv1.w * gv.w;
#pragma unroll
    for (int b = 0; b < B_; ++b) {
      const float4 xv = x4[b * (QLR_ / 4) + c4];
      acc0[b] = fmaf(wg0.x, xv.x, fmaf(wg0.y, xv.y, fmaf(wg0.z, xv.z, fmaf(wg0.w, xv.w, acc0[b]))));
      acc1[b] = fmaf(wg1.x, xv.x, fmaf(wg1.y, xv.y, fmaf(wg1.z, xv.z, fmaf(wg1.w, xv.w, acc1[b]))));
    }
  }
#pragma unroll
  for (int b = 0; b < B_; ++b)
#pragma unroll
    for (int s = 32; s; s >>= 1) {
      acc0[b] += __shfl_xor(acc0[b], s);
      acc1[b] += __shfl_xor(acc1[b], s);
    }
  if (l == 0) {
    const int h = r0 / (DN_ + DR_);
    const int j0 = r0 - h * (DN_ + DR_);
    const float b0 = bqb[r0], b1 = bqb[r0 + 1];
    if (j0 < DN_) {
      float* qn = ws + WS_QNOPE;
#pragma unroll
      for (int b = 0; b < B_; ++b) {
        const float sb = ws[WS_QRS + b];
        qn[(b * H_ + h) * DN_ + j0]     = acc0[b] * sb + b0;
        qn[(b * H_ + h) * DN_ + j0 + 1] = acc1[b] * sb + b1;
      }
    } else {
      const int i = (j0 - DN_) >> 1;
      const float c = fcos[i], s = fsin[i];
      float* qT = ws + WS_QT;
#pragma unroll
      for (int b = 0; b < B_; ++b) {
        const float sb = ws[WS_QRS + b];
        const float xr = acc0[b] * sb + b0, xi = acc1[b] * sb + b1;
        qT[((size_t)b * CE_ + KVLR_ + 2 * i) * H_ + h]     = xr * c - xi * s;
        qT[((size_t)b * CE_ + KVLR_ + 2 * i + 1) * H_ + h] = xr * s + xi * c;
      }
    }
  }
}

// ---------------- K4: q_abs[b][c][h] = sum_d q_nope[b][h][d] * wkv_b[h][d][c] ----------------
__global__ __launch_bounds__(256) void mla_k4(const float* __restrict__ wkvb,
                                              float* __restrict__ ws) {
  __shared__ float red[3 * 64 * B_];
  const int h = blockIdx.y;
  const int strip = blockIdx.x;     // 8 strips of 64 cols
  const int tid = threadIdx.x;
  const int c = tid & 63, dg = tid >> 6;  // 4 groups of 32 d
  const int cg = strip * 64 + c;
  const float* qn = ws + WS_QNOPE;
  float acc[B_];
#pragma unroll
  for (int b = 0; b < B_; ++b) acc[b] = 0.f;
  const float* wp = wkvb + (size_t)h * 256 * KVLR_ + cg;
#pragma unroll 4
  for (int dd = 0; dd < 32; ++dd) {
    const int d = dg * 32 + dd;
    const float wv = wp[(size_t)d * KVLR_];
#pragma unroll
    for (int b = 0; b < B_; ++b) acc[b] = fmaf(qn[(b * H_ + h) * DN_ + d], wv, acc[b]);
  }
  if (dg > 0) {
#pragma unroll
    for (int b = 0; b < B_; ++b) red[(((dg - 1) * 64) + c) * B_ + b] = acc[b];
  }
  __syncthreads();
  if (dg == 0) {
    float* qT = ws + WS_QT;
#pragma unroll
    for (int b = 0; b < B_; ++b) {
      const float v = acc[b] + red[c * B_ + b] + red[(64 + c) * B_ + b] + red[(128 + c) * B_ + b];
      qT[((size_t)b * CE_ + cg) * H_ + h] = v;
    }
  }
}

// ---------------- K5: flash-decode partials per (b, chunk of 128) ----------------
__global__ __launch_bounds__(512, 4) void mla_k5(const float* __restrict__ kvpre,
                                                 const float* __restrict__ pepre,
                                                 float* __restrict__ ws) {
  __shared__ float ps[4 * CT_ * 20]; // partial scores [qg][t][16 pad 20] = 40 KB
  __shared__ float pm[CT_ * H_];     // softmax p [t][h] = 8 KB
  const int b = blockIdx.y;
  const int chunk = blockIdx.x;
  const int t0 = chunk * CT_;
  const int tid = threadIdx.x;

  // ---- phase A: partial scores; thread = (column-group qg, row r) ----
  {
    const int qg = tid >> 7;        // 0..3 (wave-uniform)
    const int r  = tid & 127;
    const int t  = t0 + r;
    const float* kvrow; const float* perow;
    if (t < TPRE_) {
      kvrow = kvpre + ((size_t)b * TPRE_ + t) * KVLR_;
      perow = pepre + ((size_t)b * TPRE_ + t) * DR_;
    } else {
      kvrow = ws + WS_KVNEW + b * KVLR_;
      perow = ws + WS_PENEW + b * DR_;
    }
    const int cbase = qg * 144;
    const float* qTb = ws + WS_QT + ((size_t)b * CE_ + cbase) * H_;
    float acc[H_];
#pragma unroll
    for (int h = 0; h < H_; ++h) acc[h] = 0.f;
    auto fma4 = [&](const float4 k, const float* qc) {
#pragma unroll
      for (int h = 0; h < H_; ++h) {
        acc[h] = fmaf(qc[h],          k.x, acc[h]);
        acc[h] = fmaf(qc[H_ + h],     k.y, acc[h]);
        acc[h] = fmaf(qc[2 * H_ + h], k.z, acc[h]);
        acc[h] = fmaf(qc[3 * H_ + h], k.w, acc[h]);
      }
    };
    if (qg < 3) {
#pragma unroll 4
      for (int i = 0; i < 36; ++i)
        fma4(*(const float4*)(kvrow + cbase + 4 * i), qTb + 64 * i);
    } else {
#pragma unroll 4
      for (int i = 0; i < 20; ++i)   // kv cols 432..511
        fma4(*(const float4*)(kvrow + cbase + 4 * i), qTb + 64 * i);
#pragma unroll 4
      for (int i = 0; i < 16; ++i)   // pe cols 0..63
        fma4(*(const float4*)(perow + 4 * i), qTb + 64 * (20 + i));
    }
    float* pr = ps + ((size_t)qg * CT_ + r) * 20;
#pragma unroll
    for (int g = 0; g < 4; ++g) {
      float4 v; v.x = acc[4 * g]; v.y = acc[4 * g + 1]; v.z = acc[4 * g + 2]; v.w = acc[4 * g + 3];
      *(float4*)(pr + 4 * g) = v;
    }
  }
  __syncthreads();

  // ---- phase B: reduce column-groups + chunk-local softmax per head ----
  if (tid < 256) {
    const int h = tid >> 4, grp = tid & 15;
    float sv[8];
    float m = -3.4e38f;
#pragma unroll
    for (int j = 0; j < 8; ++j) {
      const int t = grp + 16 * j;
      const float s = (ps[(0 * CT_ + t) * 20 + h] + ps[(1 * CT_ + t) * 20 + h] +
                       ps[(2 * CT_ + t) * 20 + h] + ps[(3 * CT_ + t) * 20 + h]) * SCALE_;
      sv[j] = s;
      m = fmaxf(m, s);
    }
#pragma unroll
    for (int s = 8; s; s >>= 1) m = fmaxf(m, __shfl_xor(m, s, 16));
    float lsum = 0.f;
#pragma unroll
    for (int j = 0; j < 8; ++j) {
      const float p = __expf(sv[j] - m);
      pm[(grp + 16 * j) * H_ + h] = p;
      lsum += p;
    }
#pragma unroll
    for (int s = 8; s; s >>= 1) lsum += __shfl_xor(lsum, s, 16);
    if (grp == 0) {
      ws[WS_MLOC + (b * H_ + h) * NCH_ + chunk] = m;
      ws[WS_LLOC + (b * H_ + h) * NCH_ + chunk] = lsum;
    }
  }
  __syncthreads();

  // ---- phase C: O_partial = sum_t p * kv  (wave <-> 2 heads, lanes <-> c) ----
  {
    const int w = tid >> 6, l = tid & 63;
    const int h0 = 2 * w;
    float o[2][8];
#pragma unroll
    for (int a = 0; a < 2; ++a)
#pragma unroll
      for (int j = 0; j < 8; ++j) o[a][j] = 0.f;
    const float* kvb = kvpre + ((size_t)b * TPRE_ + t0) * KVLR_;
    const float* kvn = ws + WS_KVNEW + b * KVLR_;
    auto step = [&](const float* kr, int t) {
      const float p0 = pm[t * H_ + h0], p1 = pm[t * H_ + h0 + 1];
#pragma unroll
      for (int j = 0; j < 4; ++j) {
        const float2 kv = *(const float2*)(kr + j * 128 + 2 * l);
        o[0][2 * j]     = fmaf(p0, kv.x, o[0][2 * j]);
        o[0][2 * j + 1] = fmaf(p0, kv.y, o[0][2 * j + 1]);
        o[1][2 * j]     = fmaf(p1, kv.x, o[1][2 * j]);
        o[1][2 * j + 1] = fmaf(p1, kv.y, o[1][2 * j + 1]);
      }
    };
    if (t0 + CT_ <= TPRE_) {
#pragma unroll 2
      for (int t = 0; t < CT_; ++t) step(kvb + (size_t)t * KVLR_, t);
    } else {
      for (int t = 0; t < CT_; ++t) {
        const float* kr = (t0 + t < TPRE_) ? (kvb + (size_t)t * KVLR_) : kvn;
        step(kr, t);
      }
    }
    float* Op = ws + WS_OPART + (((size_t)(b * H_ + h0) * NCH_ + chunk) * KVLR_);
#pragma unroll
    for (int a = 0; a < 2; ++a)
#pragma unroll
      for (int j = 0; j < 4; ++j) {
        float2 v; v.x = o[a][2 * j]; v.y = o[a][2 * j + 1];
        *(float2*)(Op + (size_t)a * NCH_ * KVLR_ + j * 128 + 2 * l) = v;
      }
  }
}

// ---------------- K6: combine partials + project through wkv_b[:,128:,:] ----------------
__global__ __launch_bounds__(256) void mla_k6(const float* __restrict__ wkvb,
                                              float* __restrict__ ws) {
  const int h = blockIdx.x, b = blockIdx.y;
  __shared__ float wgt[NCH_];
  __shared__ float ao[KVLR_];
  __shared__ float Linv;
  const int tid = threadIdx.x;
  if (tid < NCH_) { // one full wave: NCH_ == 64
    const float m = ws[WS_MLOC + (b * H_ + h) * NCH_ + tid];
    float M = m;
#pragma unroll
    for (int s = 32; s; s >>= 1) M = fmaxf(M, __shfl_xor(M, s));
    const float wv = __expf(m - M);
    wgt[tid] = wv;
    float lv = ws[WS_LLOC + (b * H_ + h) * NCH_ + tid] * wv;
#pragma unroll
    for (int s = 32; s; s >>= 1) lv += __shfl_xor(lv, s);
    if (tid == 0) Linv = 1.0f / lv;
  }
  __syncthreads();
  const float* Ob = ws + WS_OPART + (size_t)(b * H_ + h) * NCH_ * KVLR_;
  float s0 = 0.f, s1 = 0.f;
#pragma unroll 4
  for (int i = 0; i < NCH_; ++i) {
    const float wv = wgt[i];
    s0 = fmaf(wv, Ob[(size_t)i * KVLR_ + tid], s0);
    s1 = fmaf(wv, Ob[(size_t)i * KVLR_ + tid + 256], s1);
  }
  const float li = Linv;
  ao[tid] = s0 * li;
  ao[tid + 256] = s1 * li;
  __syncthreads();
  const int v = tid >> 1, half = tid & 1;
  const float* w2 = wkvb + ((size_t)h * 256 + DN_ + v) * KVLR_ + half * 256;
  const float* a = ao + half * 256;
  float s = 0.f;
#pragma unroll
  for (int c = 0; c < 256; c += 4) {
    const float4 wv = *(const float4*)(w2 + c);
    s = fmaf(wv.x, a[c], s);
    s = fmaf(wv.y, a[c + 1], s);
    s = fmaf(wv.z, a[c + 2], s);
    s = fmaf(wv.w, a[c + 3], s);
  }
  s += __shfl_xor(s, 1);
  if (half == 0) ws[WS_OUT2 + b * DIM_ + h * DV_ + v] = s;
}

// ---------------- K7: y = out2 @ wo^T + wo_b ----------------
__global__ __launch_bounds__(512) void mla_k7(const float* __restrict__ wo,
                                              const float* __restrict__ wob,
                                              const float* __restrict__ ws,
                                              float* __restrict__ out) {
  const int w = threadIdx.x >> 6, l = threadIdx.x & 63;
  const int r = blockIdx.x * 8 + w;  // 0..2047
  float acc[B_];
#pragma unroll
  for (int b = 0; b < B_; ++b) acc[b] = 0.f;
  const float4* wp = (const float4*)(wo + (size_t)r * DIM_);
  const float4* x4 = (const float4*)(ws + WS_OUT2);
#pragma unroll
  for (int j = 0; j < DIM_ / 256; ++j) { // 8
    const int c4 = l + 64 * j;
    const float4 wv = wp[c4];
#pragma unroll
    for (int b = 0; b < B_; ++b) {
      const float4 xv = x4[b * (DIM_ / 4) + c4];
      acc[b] = fmaf(wv.x, xv.x, fmaf(wv.y, xv.y, fmaf(wv.z, xv.z, fmaf(wv.w, xv.w, acc[b]))));
    }
  }
#pragma unroll
  for (int b = 0; b < B_; ++b)
#pragma unroll
    for (int s = 32; s; s >>= 1) acc[b] += __shfl_xor(acc[b], s);
  if (l == 0) {
    const float b0 = wob[r];
#pragma unroll
    for (int b = 0; b < B_; ++b) out[b * DIM_ + r] = acc[b] + b0;
  }
}

extern "C" void kernel_launch(void* const* d_in, const int* in_sizes, int n_in,
                              void* d_out, int out_size, void* d_ws, size_t ws_size,
                              hipStream_t stream) {
  (void)in_sizes; (void)n_in; (void)out_size; (void)ws_size;
  const float* x     = (const float*)d_in[0];
  const float* fcos  = (const float*)d_in[2];
  const float* fsin  = (const float*)d_in[3];
  const float* kvpre = (const float*)d_in[4];
  const float* pepre = (const float*)d_in[5];
  const float* wqa   = (const float*)d_in[6];
  const float* bqa   = (const float*)d_in[7];
  const float* qnw   = (const float*)d_in[8];
  const float* wqb   = (const float*)d_in[9];
  const float* bqb   = (const float*)d_in[10];
  const float* wkva  = (const float*)d_in[11];
  const float* bkva  = (const float*)d_in[12];
  const float* kvnw  = (const float*)d_in[13];
  const float* wkvb  = (const float*)d_in[14];
  const float* wo    = (const float*)d_in[15];
  const float* wob   = (const float*)d_in[16];
  float* ws  = (float*)d_ws;
  float* out = (float*)d_out;

  mla_k1<<<dim3((QLR_ + CE_) / 8), dim3(512), 0, stream>>>(x, wqa, bqa, wkva, bkva, ws);
  mla_k2<<<dim3(1), dim3(256), 0, stream>>>(kvnw, fcos, fsin, ws);
  mla_k3<<<dim3(H_ * (DN_ + DR_) / 8), dim3(256), 0, stream>>>(qnw, wqb, bqb, fcos, fsin, ws);
  mla_k4<<<dim3(8, H_), dim3(256), 0, stream>>>(wkvb, ws);
  mla_k5<<<dim3(NCH_, B_), dim3(512), 0, stream>>>(kvpre, pepre, ws);
  mla_k6<<<dim3(H_, B_), dim3(256), 0, stream>>>(wkvb, ws);
  mla_k7<<<dim3(DIM_ / 8), dim3(512), 0, stream>>>(wo, wob, ws, out);
}